// Round 2
// 625.021 us; speedup vs baseline: 1.0868x; 1.0868x over previous
//
#include <hip/hip_runtime.h>
#include <hip/hip_bf16.h>
#include <stdint.h>

// RandLinear: out[n,o] = sum_i x[n,i] * (mu_w[o,i] + exp(ls_w[o,i])*eps_w[o,i]) + bias[o]
// Strategy: materialize W and x in bf16, then 256x256-tile bf16 GEMM-BT with a
// counted-vmcnt 4-deep LDS pipeline (T1+T2+T3/T4+T5 from the CDNA4 catalog):
//  - BK=32, 4 LDS tile-buffers (128 KiB): stage tile t+3 while computing tile t.
//  - Raw s_barrier + inline-asm s_waitcnt vmcnt(8) per K-step: 2 tiles' loads
//    (8 per thread) stay in flight ACROSS the barrier (never drain to 0 in loop).
//  - LDS XOR-swizzle: physical 16B slot = quad ^ ((row>>1)&3); applied on the
//    global SOURCE address of global_load_lds (linear LDS dest) and on ds_read.
//  - s_setprio(1) around the 32-MFMA cluster; XCD-chunked blockIdx swizzle.
// FIX vs last attempt: global_load_lds LDS-destination operand must be
// WAVE-UNIFORM (HW adds lane*16 itself; m104/m108). Last attempt passed a
// per-lane pointer (undefined -> suspected GPU fault). Now we pass the uniform
// wave chunk base; per-lane addressing lives only on the global source side.

constexpr int M    = 8192;  // rows of x ("N" in reference)
constexpr int K    = 4096;  // IN
constexpr int NOUT = 4096;  // OUT

typedef __bf16 bf16x8 __attribute__((ext_vector_type(8)));
typedef float  f32x4  __attribute__((ext_vector_type(4)));
typedef short  short8 __attribute__((ext_vector_type(8)));

#define DI __device__ __forceinline__

DI void gl_lds16(const void* g, void* l) {
  __builtin_amdgcn_global_load_lds(
      (__attribute__((address_space(1))) void*)(g),
      (__attribute__((address_space(3))) void*)(l),
      16, 0, 0);
}

union BF8 {
  __hip_bfloat16 h[8];
  short8 s;
};

// ---- cast x (fp32 -> bf16), 8 elems/thread ----
__global__ __launch_bounds__(256) void cast_x_kernel(const float* __restrict__ x,
                                                     short* __restrict__ xb) {
  int i = blockIdx.x * 256 + threadIdx.x;  // chunk of 8 floats
  const float4* src = (const float4*)x;
  float4 f0 = src[2 * i + 0];
  float4 f1 = src[2 * i + 1];
  BF8 u;
  u.h[0] = __float2bfloat16(f0.x);
  u.h[1] = __float2bfloat16(f0.y);
  u.h[2] = __float2bfloat16(f0.z);
  u.h[3] = __float2bfloat16(f0.w);
  u.h[4] = __float2bfloat16(f1.x);
  u.h[5] = __float2bfloat16(f1.y);
  u.h[6] = __float2bfloat16(f1.z);
  u.h[7] = __float2bfloat16(f1.w);
  ((short8*)xb)[i] = u.s;
}

// ---- W = mu + exp(ls)*eps, cast to bf16, 8 elems/thread ----
__global__ __launch_bounds__(256) void w_fuse_kernel(const float* __restrict__ mu,
                                                     const float* __restrict__ ls,
                                                     const float* __restrict__ eps,
                                                     short* __restrict__ wb) {
  int i = blockIdx.x * 256 + threadIdx.x;
  const float4* mu4 = (const float4*)mu;
  const float4* ls4 = (const float4*)ls;
  const float4* ep4 = (const float4*)eps;
  float4 m0 = mu4[2 * i + 0], m1 = mu4[2 * i + 1];
  float4 l0 = ls4[2 * i + 0], l1 = ls4[2 * i + 1];
  float4 e0 = ep4[2 * i + 0], e1 = ep4[2 * i + 1];
  BF8 u;
  u.h[0] = __float2bfloat16(m0.x + __expf(l0.x) * e0.x);
  u.h[1] = __float2bfloat16(m0.y + __expf(l0.y) * e0.y);
  u.h[2] = __float2bfloat16(m0.z + __expf(l0.z) * e0.z);
  u.h[3] = __float2bfloat16(m0.w + __expf(l0.w) * e0.w);
  u.h[4] = __float2bfloat16(m1.x + __expf(l1.x) * e1.x);
  u.h[5] = __float2bfloat16(m1.y + __expf(l1.y) * e1.y);
  u.h[6] = __float2bfloat16(m1.z + __expf(l1.z) * e1.z);
  u.h[7] = __float2bfloat16(m1.w + __expf(l1.w) * e1.w);
  ((short8*)wb)[i] = u.s;
}

// ---- bias = mu_b + exp(ls_b)*eps_b (fp32) ----
__global__ __launch_bounds__(256) void bias_kernel(const float* __restrict__ mu_b,
                                                   const float* __restrict__ ls_b,
                                                   const float* __restrict__ eps_b,
                                                   float* __restrict__ bias) {
  int i = blockIdx.x * 256 + threadIdx.x;
  if (i < NOUT) bias[i] = mu_b[i] + expf(ls_b[i]) * eps_b[i];
}

// ---- GEMM: C[m,n] = sum_k A[m,k]*B[n,k] + bias[n]  (A:[M,K] bf16, B:[N,K] bf16)
// 256x256 tile, BK=32, 512 threads (8 waves = 2M x 4N), per-wave C = 128x64.
constexpr int BM = 256, BN = 256, BK = 32;
constexpr int NT = K / BK;  // 128 K-steps

__global__ __launch_bounds__(512, 2) void gemm_bt_kernel(const short* __restrict__ A,
                                                         const short* __restrict__ B,
                                                         const float* __restrict__ bias,
                                                         float* __restrict__ C) {
  // 4 tile-buffers x (A 16 KiB + B 16 KiB) = 128 KiB total.
  __shared__ __align__(16) short Alds[4][BM * BK];
  __shared__ __align__(16) short Blds[4][BN * BK];

  const int tid  = threadIdx.x;
  const int lane = tid & 63;
  const int wave = tid >> 6;   // 0..7
  const int wm   = wave >> 2;  // 0..1 : which 128-row half of the 256-row tile
  const int wn   = wave & 3;   // 0..3 : which 64-col quarter
  const int mrow = lane & 15;
  const int quad = lane >> 4;

  // XCD-chunked swizzle: 512 wgs, 8 XCDs -> 64 consecutive per XCD (512%8==0).
  const int bid = blockIdx.x;
  const int swz = (bid & 7) * 64 + (bid >> 3);
  const int m0  = (swz >> 4) * BM;  // 32 row-tiles
  const int n0  = (swz & 15) * BN;  // 16 col-tiles

  // ---- staging precompute ----
  // Tile = 1024 chunks of 16B; chunk c: row = c>>2, PHYSICAL slot sp = c&3.
  // Swizzle (involution): logical slot sl = sp ^ ((row>>1)&3).
  // global_load_lds writes linearly at uniform_base + lane*16; the swizzle is
  // applied by reading the pre-swizzled GLOBAL source (linear dest + swz source).
  const int c0 = tid, c1 = 512 + tid;     // per-lane chunk ids (for global addr)
  const int cb0 = (wave << 6);            // WAVE-UNIFORM lds chunk base (lane 0)
  const int cb1 = 512 + (wave << 6);
  const int r0 = c0 >> 2, r1 = c1 >> 2;
  const int sl0 = (c0 & 3) ^ ((r0 >> 1) & 3);
  const int sl1 = (c1 & 3) ^ ((r1 >> 1) & 3);
  const short* gA0 = A + (size_t)(m0 + r0) * K + sl0 * 8;
  const short* gA1 = A + (size_t)(m0 + r1) * K + sl1 * 8;
  const short* gB0 = B + (size_t)(n0 + r0) * K + sl0 * 8;
  const short* gB1 = B + (size_t)(n0 + r1) * K + sl1 * 8;

  // ---- ds_read bases (bytes), with the same swizzle on the read side ----
  // Row stride 64B; lane wants k-span quad*8.. -> physical slot quad^((row>>1)&3),
  // where (row>>1)&3 == (mrow>>1)&3 since the row base is a multiple of 16.
  const int slot = quad ^ ((mrow >> 1) & 3);
  const int aOff = (wm * 128 + mrow) * 64 + slot * 16;
  const int bOff = (wn * 64 + mrow) * 64 + slot * 16;

  f32x4 acc[8][4] = {};

// stage tile tt into buffer tt&3: 4 vmem loads per thread (A x2, B x2).
// LDS dest = wave-uniform base; HW adds lane*16 (matches per-lane global addr).
#define STAGE(tt)                                           \
  do {                                                      \
    const int _b = (tt) & 3;                                \
    const int _k = (tt) * BK;                               \
    gl_lds16(gA0 + _k, (char*)Alds[_b] + cb0 * 16);         \
    gl_lds16(gA1 + _k, (char*)Alds[_b] + cb1 * 16);         \
    gl_lds16(gB0 + _k, (char*)Blds[_b] + cb0 * 16);         \
    gl_lds16(gB1 + _k, (char*)Blds[_b] + cb1 * 16);         \
  } while (0)

// compute tile tt from buffer tt&3: 12 ds_read_b128 + 32 MFMA per wave
#define COMPUTE(tt)                                                              \
  do {                                                                           \
    const char* _Ab = (const char*)Alds[(tt) & 3] + aOff;                        \
    const char* _Bb = (const char*)Blds[(tt) & 3] + bOff;                        \
    bf16x8 a[8], b[4];                                                           \
    _Pragma("unroll") for (int mi = 0; mi < 8; ++mi)                             \
        a[mi] = *(const bf16x8*)(_Ab + mi * 1024);                               \
    _Pragma("unroll") for (int ni = 0; ni < 4; ++ni)                             \
        b[ni] = *(const bf16x8*)(_Bb + ni * 1024);                               \
    __builtin_amdgcn_s_setprio(1);                                               \
    _Pragma("unroll") for (int mi = 0; mi < 8; ++mi)                             \
        _Pragma("unroll") for (int ni = 0; ni < 4; ++ni)                         \
            acc[mi][ni] =                                                        \
                __builtin_amdgcn_mfma_f32_16x16x32_bf16(a[mi], b[ni],            \
                                                        acc[mi][ni], 0, 0, 0);  \
    __builtin_amdgcn_s_setprio(0);                                               \
  } while (0)

  // Prologue: stage tiles 0,1,2 (12 loads in flight), confirm tile 0 landed.
  STAGE(0);
  STAGE(1);
  STAGE(2);
  asm volatile("s_waitcnt vmcnt(8)" ::: "memory");
  __builtin_amdgcn_s_barrier();

  // Main loop: compute t, stage t+3. vmcnt(8) leaves tiles t+2,t+3 in flight
  // across the barrier (counted-vmcnt: never drain to 0 in the loop).
#pragma unroll 4
  for (int t = 0; t < NT - 3; ++t) {
    STAGE(t + 3);
    COMPUTE(t);
    asm volatile("s_waitcnt vmcnt(8)" ::: "memory");
    __builtin_amdgcn_s_barrier();
  }
  // Epilogue: drain 8 -> 4 -> 0.
  COMPUTE(NT - 3);
  asm volatile("s_waitcnt vmcnt(4)" ::: "memory");
  __builtin_amdgcn_s_barrier();
  COMPUTE(NT - 2);
  asm volatile("s_waitcnt vmcnt(0)" ::: "memory");
  __builtin_amdgcn_s_barrier();
  COMPUTE(NT - 1);

#undef STAGE
#undef COMPUTE

  // C-write: C/D layout col = lane&15, row = quad*4 + reg.
#pragma unroll
  for (int ni = 0; ni < 4; ++ni) {
    const int col  = n0 + wn * 64 + ni * 16 + mrow;
    const float bv = bias[col];
#pragma unroll
    for (int mi = 0; mi < 8; ++mi) {
      const int rowb = m0 + wm * 128 + mi * 16 + quad * 4;
#pragma unroll
      for (int r = 0; r < 4; ++r)
        C[(size_t)(rowb + r) * NOUT + col] = acc[mi][ni][r] + bv;
    }
  }
}

extern "C" void kernel_launch(void* const* d_in, const int* in_sizes, int n_in,
                              void* d_out, int out_size, void* d_ws, size_t ws_size,
                              hipStream_t stream) {
  const float* x    = (const float*)d_in[0];
  const float* mu_w = (const float*)d_in[1];
  const float* ls_w = (const float*)d_in[2];
  const float* mu_b = (const float*)d_in[3];
  const float* ls_b = (const float*)d_in[4];
  const float* ep_w = (const float*)d_in[5];
  const float* ep_b = (const float*)d_in[6];
  float* out = (float*)d_out;

  // Workspace layout
  char* ws = (char*)d_ws;
  short* xb   = (short*)(ws);                                  // M*K bf16   = 64 MiB
  short* wb   = (short*)(ws + (size_t)M * K * 2);              // NOUT*K bf16= 32 MiB
  float* bias = (float*)(ws + (size_t)M * K * 2 + (size_t)NOUT * K * 2);

  cast_x_kernel<<<(M * (size_t)K) / 8 / 256, 256, 0, stream>>>(x, xb);
  w_fuse_kernel<<<((size_t)NOUT * K) / 8 / 256, 256, 0, stream>>>(mu_w, ls_w, ep_w, wb);
  bias_kernel<<<(NOUT + 255) / 256, 256, 0, stream>>>(mu_b, ls_b, ep_b, bias);

  gemm_bt_kernel<<<(M / BM) * (NOUT / BN), 512, 0, stream>>>(xb, wb, bias, out);
}